// Round 18
// baseline (92.510 us; speedup 1.0000x reference)
//
#include <hip/hip_runtime.h>
#include <stdint.h>

#define NFFT    1024
#define HOP     160
#define NMELS   160
#define SEG     32000
#define PADW    512
#define NFRAMES 201
#define NBATCH  256
#define NSTEP   16               // K-steps of 32 over K=512 (symmetry-folded)
#define ROWB    336              // padded row bytes (160 samples + 8 pad)
#define NROWS   230
#define WPCH    (NROWS * 21)     // 4830 u4 chunks per batch
#define WPB2    (WPCH * 8)       // 38,640 halfwords per batch
#define FILLCH  2496             // fill chunks (118 rows = 2478, rounded up)
#define YOFF    39648            // yrow LDS base (= 118*336)
#define PW_OFF  39648            // power tile overlays yrow after K-loop
#define LDS_TOTAL 96992          // PW_OFF + 112*512 bf16 tile (57344)

using bf16x8 = __attribute__((ext_vector_type(8))) __bf16;
using f32x4  = __attribute__((ext_vector_type(4))) float;
using u32x4v = __attribute__((ext_vector_type(4))) unsigned int;

static __device__ __forceinline__ uint16_t f2bf(float f) {
    union { float f; uint32_t u; } v; v.f = f;
    return (uint16_t)((v.u + 0x7FFFu + ((v.u >> 16) & 1u)) >> 16);
}
static __device__ __forceinline__ float bf2f(uint16_t h) {
    union { uint32_t u; float f; } v; v.u = (uint32_t)h << 16;
    return v.f;
}
static __device__ __forceinline__ void gload16(const void* g, void* l) {
    __builtin_amdgcn_global_load_lds(
        (const __attribute__((address_space(1))) uint32_t*)(uintptr_t)g,
        (__attribute__((address_space(3))) uint32_t*)(uintptr_t)l,
        16, 0, 0);
}

// ==== fused prep: pad(row-layout) | btfs(K=512 frag-major) | fbT ====
#define PAD_BLKS  (NBATCH * 19)   // 4864
#define BTFS_BLKS 128             // 32768 threads: 32 vfrags x 16 ksteps x 64
#define FBT_BLKS  20
#define PREP_GRID (PAD_BLKS + BTFS_BLKS + FBT_BLKS)

__global__ void k_prep(const float* __restrict__ wav, const float* __restrict__ win,
                       const float* __restrict__ dre, const float* __restrict__ dimg,
                       const float* __restrict__ mfb,
                       uint16_t* __restrict__ wp2, uint16_t* __restrict__ BTfs,
                       uint16_t* __restrict__ fbT) {
    int bid = blockIdx.x, tid = threadIdx.x;
    if (bid < PAD_BLKS) {
        int b = bid / 19, ib = bid - b * 19;
        int chunk = ib * 256 + tid;
        if (chunk >= WPCH) return;
        int row = chunk / 21, cc = chunk - row * 21;
        uint16_t r[8] = {0,0,0,0,0,0,0,0};
        if (cc < 20) {
            int s0 = row * 160 + cc * 8;
            if (s0 >= PADW && s0 + 8 <= PADW + SEG) {
                const float* s = wav + (size_t)b * SEG + (s0 - PADW);
                float4 v0 = *(const float4*)s;
                float4 v1 = *(const float4*)(s + 4);
                r[0]=f2bf(v0.x); r[1]=f2bf(v0.y); r[2]=f2bf(v0.z); r[3]=f2bf(v0.w);
                r[4]=f2bf(v1.x); r[5]=f2bf(v1.y); r[6]=f2bf(v1.z); r[7]=f2bf(v1.w);
            } else {
                #pragma unroll
                for (int e = 0; e < 8; ++e) {
                    int i = s0 + e - PADW;
                    int j = (i < 0) ? -i : ((i >= SEG) ? (2 * SEG - 2 - i) : i);
                    r[e] = f2bf(wav[(size_t)b * SEG + j]);
                }
            }
        }
        *(uint4*)(wp2 + (size_t)b * WPB2 + (size_t)chunk * 8) = *(const uint4*)r;
    } else if (bid < PAD_BLKS + BTFS_BLKS) {
        // BTfs frag-major, K=512: ((mat*16+ntile)*16 + kstep)*64 + lane, x8 hw.
        // value = (mat? -w sin : w cos)[bin][n] = (mat? dimg : dre)*win, n < 512.
        int idx8 = (bid - PAD_BLKS) * 256 + tid;       // 0..32767
        int lane  = idx8 & 63;
        int kstep = (idx8 >> 6) & 15;
        int ntile = (idx8 >> 10) & 15;
        int mat   = idx8 >> 14;
        int bin = ntile * 16 + (lane & 15);
        int k0  = kstep * 32 + (lane >> 4) * 8;
        const float* src = (mat ? dimg : dre) + (size_t)bin * 1024 + k0;
        const float* w   = win + k0;
        uint16_t r[8];
        #pragma unroll
        for (int j = 0; j < 8; ++j) r[j] = f2bf(src[j] * w[j]);
        *(uint4*)(BTfs + (size_t)idx8 * 8) = *(const uint4*)r;
    } else {
        // fbT frag-major dense: ((mt*8 + kf)*64 + lane)*8
        int idx = (bid - PAD_BLKS - BTFS_BLKS) * 256 + tid;
        if (idx >= 5120) return;
        int lane = idx & 63;
        int fI = idx >> 6;
        int kf = fI & 7, mt = fI >> 3;
        int mel = mt * 16 + (lane & 15);
        int b0  = kf * 32 + (lane >> 4) * 8;
        const float* s = mfb + (size_t)mel * 513 + b0;
        uint16_t r[8];
        #pragma unroll
        for (int j = 0; j < 8; ++j) r[j] = f2bf(s[j]);
        *(uint4*)(fbT + (size_t)idx * 8) = *(const uint4*)r;
    }
}

// ==== main: block = (batch, frame-half). 512 blocks, 8 waves, 1M x 8N.
// HERMITIAN-FOLDED DFT (K=512): R = cw·u + (-1)^bin x512 ; I = sw·v with
// u/v[n] = x[n] +/- x[1024-n], formed IN REGISTERS per wave from two LDS
// buffers: fwd rows (118x336B) and yrow (reversed image, built in-kernel by a
// one-time VALU pass; yrow[q][m] = x[160(q-3)+1024-m] makes the reversed
// operand an ALIGNED ASCENDING ds_read_b128). 16 K-steps, 28 MFMA each
// (halved MFMA work). No setprio; 3-ring 2-deep B prefetch; barrier-free loop.
// Epilogue: rank-1 x512 correction + power -> pw[112][256] bf16 (rotation
// swizzle) -> mel MFMA GEMM (R17) -> predicated coalesced stores.
__global__ __launch_bounds__(512, 1) void k_main(
    const uint16_t* __restrict__ wp2, const uint16_t* __restrict__ BTfs,
    const uint16_t* __restrict__ fbT, float* __restrict__ out)
{
    __shared__ uint4 smem4[LDS_TOTAL / 16];
    char* smem = (char*)smem4;

    const int tid  = threadIdx.x;
    const int lane = tid & 63;
    const int wn   = tid >> 6;               // wave = N-slice
    const int l15 = lane & 15, lg = lane >> 4;
    const int b    = blockIdx.x;
    const int h    = blockIdx.y;
    const int r0   = h ? 96 : 0;             // first frame row of this half

    // ---- fill fwd rows r0..r0+117
    const uint16_t* wsrc = wp2 + (size_t)b * WPB2 + (size_t)r0 * 168;
    #pragma unroll
    for (int i = 0; i < 4; ++i)
        gload16(wsrc + (size_t)(tid + i * 512) * 8, smem + (size_t)(tid + i * 512) * 16);
    if (tid < FILLCH - 2048)
        gload16(wsrc + (size_t)(tid + 2048) * 8, smem + (size_t)(tid + 2048) * 16);
    asm volatile("s_waitcnt vmcnt(0)" ::: "memory");
    __syncthreads();

    // ---- build yrow (reversed image), 115 rows x 20 chunks, from fwd LDS
    for (int ch = tid; ch < 115 * 20; ch += 512) {
        int q = ch / 20, c = ch - q * 20;    // out: yrow[q][8c..8c+7]
        int s0 = 160 * q + 544 - 8 * c;      // source sample for j=0
        int sA = s0 - 8;
        uint4 A = *(const uint4*)(smem + (sA / 160) * ROWB + (sA % 160) * 2);
        uint4 B = *(const uint4*)(smem + (s0 / 160) * ROWB + (s0 % 160) * 2);
        uint32_t d0 = (B.x & 0xffffu) | (A.w & 0xffff0000u);
        uint32_t d1 = (A.w & 0xffffu) | (A.z & 0xffff0000u);
        uint32_t d2 = (A.z & 0xffffu) | (A.y & 0xffff0000u);
        uint32_t d3 = (A.y & 0xffffu) | (A.x & 0xffff0000u);
        *(uint4*)(smem + YOFF + q * ROWB + c * 16) = uint4{d0, d1, d2, d3};
    }
    __syncthreads();

    const uint32_t alane = (uint32_t)(l15 * ROWB + lg * 16);
    const uint16_t* bp = BTfs + (size_t)(wn * 2) * 8192 + lane * 8;

    f32x4 acc[7][4];                         // 0,1 = R(cw) ntiles; 2,3 = I(sw)
    #pragma unroll
    for (int fi = 0; fi < 7; ++fi)
        #pragma unroll
        for (int nf = 0; nf < 4; ++nf)
            acc[fi][nf] = f32x4{0.f, 0.f, 0.f, 0.f};

    bf16x8 bvA[4], bvB[4], bvC[4];

    #define LOADB(dst, t) { \
        dst[0] = *(const bf16x8*)(bp + (size_t)(t) * 512); \
        dst[1] = *(const bf16x8*)(bp + 8192 + (size_t)(t) * 512); \
        dst[2] = *(const bf16x8*)(bp + 131072 + (size_t)(t) * 512); \
        dst[3] = *(const bf16x8*)(bp + 131072 + 8192 + (size_t)(t) * 512); }

    #define FORM_MFMA(fi, t, bv) { \
        u32x4v xf = *(const u32x4v*)(smem + alane + \
            (uint32_t)((fi) * 16 * ROWB + ((t) / 5) * ROWB + ((32 * (t)) % 160) * 2)); \
        u32x4v xr = *(const u32x4v*)(smem + alane + \
            (uint32_t)(YOFF + ((fi) * 16 + 3 - (t) / 5) * ROWB + ((32 * (t)) % 160) * 2)); \
        bf16x8 uu, vv; \
        _Pragma("unroll") \
        for (int d = 0; d < 4; ++d) { \
            float alo = __uint_as_float(xf[d] << 16); \
            float ahi = __uint_as_float(xf[d] & 0xffff0000u); \
            float blo = __uint_as_float(xr[d] << 16); \
            float bhi = __uint_as_float(xr[d] & 0xffff0000u); \
            float ulo = alo + blo, uhi = ahi + bhi; \
            float vlo = alo - blo, vhi = ahi - bhi; \
            uint32_t ud, vd; \
            asm("v_cvt_pk_bf16_f32 %0, %1, %2" : "=v"(ud) : "v"(ulo), "v"(uhi)); \
            asm("v_cvt_pk_bf16_f32 %0, %1, %2" : "=v"(vd) : "v"(vlo), "v"(vhi)); \
            ((u32x4v*)&uu)[0][d] = ud; ((u32x4v*)&vv)[0][d] = vd; \
        } \
        acc[fi][0] = __builtin_amdgcn_mfma_f32_16x16x32_bf16(uu, bv[0], acc[fi][0], 0, 0, 0); \
        acc[fi][1] = __builtin_amdgcn_mfma_f32_16x16x32_bf16(uu, bv[1], acc[fi][1], 0, 0, 0); \
        acc[fi][2] = __builtin_amdgcn_mfma_f32_16x16x32_bf16(vv, bv[2], acc[fi][2], 0, 0, 0); \
        acc[fi][3] = __builtin_amdgcn_mfma_f32_16x16x32_bf16(vv, bv[3], acc[fi][3], 0, 0, 0); }

    LOADB(bvA, 0);
    LOADB(bvB, 1);
    #pragma unroll
    for (int t = 0; t < NSTEP; ++t) {
        if (t + 2 < NSTEP) {
            const int n2 = (t + 2) % 3;
            if      (n2 == 0) { LOADB(bvA, t + 2); }
            else if (n2 == 1) { LOADB(bvB, t + 2); }
            else              { LOADB(bvC, t + 2); }
        }
        const int c = t % 3;
        #pragma unroll
        for (int fi = 0; fi < 7; ++fi) {
            if      (c == 0) { FORM_MFMA(fi, t, bvA); }
            else if (c == 1) { FORM_MFMA(fi, t, bvB); }
            else             { FORM_MFMA(fi, t, bvC); }
        }
    }
    __syncthreads();                         // yrow dead; pw overlays it

    // ---- rank-1 x512 correction + power -> pw[112][256] bf16 (rot swizzle)
    const float sgn = (l15 & 1) ? -1.f : 1.f;
    #pragma unroll
    for (int fi = 0; fi < 7; ++fi)
        #pragma unroll
        for (int e = 0; e < 4; ++e) {
            const int frow = fi * 16 + lg * 4 + e;
            const float c512 = bf2f(*(const uint16_t*)(smem + (frow + 3) * ROWB + 64));
            #pragma unroll
            for (int nt = 0; nt < 2; ++nt) {
                const int bin = (wn * 2 + nt) * 16 + l15;
                float r  = acc[fi][nt][e] + sgn * c512;
                float im = acc[fi][nt + 2][e];
                const int slot = ((bin >> 3) + frow) & 31;
                *(uint16_t*)(smem + PW_OFF + frow * 512 + slot * 16 + (bin & 7) * 2)
                    = f2bf(r * r + im * im);
            }
        }
    __syncthreads();

    // ---- mel GEMM: out[m][f] = sum_k fb[m][k] pw[f][k]; 70 tasks round-robin
    float* obase = out + (size_t)b * (NMELS * NFRAMES);
    for (int task = wn; task < 70; task += 8) {
        const int mt = task / 7, ft = task - mt * 7;
        f32x4 d = f32x4{0.f, 0.f, 0.f, 0.f};
        const int frame = ft * 16 + l15;
        #pragma unroll
        for (int kf = 0; kf < 8; ++kf) {
            bf16x8 a = *(const bf16x8*)(fbT + (size_t)((mt * 8 + kf) * 64 + lane) * 8);
            const int slot = (kf * 4 + lg + frame) & 31;
            bf16x8 bb = *(const bf16x8*)(smem + PW_OFF + frame * 512 + slot * 16);
            d = __builtin_amdgcn_mfma_f32_16x16x32_bf16(a, bb, d, 0, 0, 0);
        }
        const int fg = r0 + frame;
        const bool own = h ? (fg >= 104 && fg <= 200) : (fg <= 103);
        if (own) {
            #pragma unroll
            for (int e = 0; e < 4; ++e)
                obase[(mt * 16 + lg * 4 + e) * NFRAMES + fg] = d[e];
        }
    }
}

extern "C" void kernel_launch(void* const* d_in, const int* in_sizes, int n_in,
                              void* d_out, int out_size, void* d_ws, size_t ws_size,
                              hipStream_t stream) {
    const float* wav  = (const float*)d_in[0];
    const float* win  = (const float*)d_in[1];
    const float* dre  = (const float*)d_in[2];
    const float* dimg = (const float*)d_in[3];
    const float* mfb  = (const float*)d_in[4];
    float* out = (float*)d_out;

    uint8_t* ws = (uint8_t*)d_ws;
    uint16_t* BTfs = (uint16_t*)ws;                          // 512 KB folded DFT
    uint16_t* wp2  = (uint16_t*)(ws + (1u << 20));           // 19.8 MB padded wave
    size_t off = (1u << 20) + (size_t)NBATCH * WPB2 * 2;
    uint16_t* fbT = (uint16_t*)(ws + off);                   // 80 KB mel fb frags

    hipLaunchKernelGGL(k_prep, dim3(PREP_GRID), dim3(256), 0, stream,
                       wav, win, dre, dimg, mfb, wp2, BTfs, fbT);
    hipLaunchKernelGGL(k_main, dim3(NBATCH, 2), dim3(512), 0, stream,
                       wp2, BTfs, fbT, out);
}

// Round 19
// 81.738 us; speedup vs baseline: 1.1318x; 1.1318x over previous
//
#include <hip/hip_runtime.h>
#include <stdint.h>

#define NFFT    1024
#define HOP     160
#define NMELS   160
#define SEG     32000
#define PADW    512
#define NFRAMES 201
#define NBATCH  256
#define NSTEP   32               // K-steps of 32
#define ROWB    336              // padded row bytes (160 samples + 8 pad)
#define NROWS   230
#define WPCH    (NROWS * 21)     // 4830 u4 chunks per batch
#define WPB2    (WPCH * 8)       // 38,640 halfwords per batch
#define FILLCH  2496             // chunks per half fill (118 rows + align)

using bf16x8 = __attribute__((ext_vector_type(8))) __bf16;
using f32x4  = __attribute__((ext_vector_type(4))) float;

static __device__ __forceinline__ uint16_t f2bf(float f) {
    union { float f; uint32_t u; } v; v.f = f;
    return (uint16_t)((v.u + 0x7FFFu + ((v.u >> 16) & 1u)) >> 16);
}
static __device__ __forceinline__ void gload16(const void* g, void* l) {
    __builtin_amdgcn_global_load_lds(
        (const __attribute__((address_space(1))) uint32_t*)(uintptr_t)g,
        (__attribute__((address_space(3))) uint32_t*)(uintptr_t)l,
        16, 0, 0);
}

// ==== fused prep: pad(row-layout) | btf(frag-major) | fbT(frag-major dense) ====
#define PAD_BLKS  (NBATCH * 19)   // 4864
#define BTF_BLKS  256
#define FBT_BLKS  20              // 5120 threads: 80 frags x 64 lanes
#define PREP_GRID (PAD_BLKS + BTF_BLKS + FBT_BLKS)

__global__ void k_prep(const float* __restrict__ wav, const float* __restrict__ win,
                       const float* __restrict__ dre, const float* __restrict__ dimg,
                       const float* __restrict__ mfb,
                       uint16_t* __restrict__ wp2, uint16_t* __restrict__ BTf,
                       uint16_t* __restrict__ fbT) {
    int bid = blockIdx.x, tid = threadIdx.x;
    if (bid < PAD_BLKS) {
        int b = bid / 19, ib = bid - b * 19;
        int chunk = ib * 256 + tid;
        if (chunk >= WPCH) return;
        int row = chunk / 21, cc = chunk - row * 21;
        uint16_t r[8] = {0,0,0,0,0,0,0,0};
        if (cc < 20) {
            int s0 = row * 160 + cc * 8;
            if (s0 >= PADW && s0 + 8 <= PADW + SEG) {
                const float* s = wav + (size_t)b * SEG + (s0 - PADW);
                float4 v0 = *(const float4*)s;
                float4 v1 = *(const float4*)(s + 4);
                r[0]=f2bf(v0.x); r[1]=f2bf(v0.y); r[2]=f2bf(v0.z); r[3]=f2bf(v0.w);
                r[4]=f2bf(v1.x); r[5]=f2bf(v1.y); r[6]=f2bf(v1.z); r[7]=f2bf(v1.w);
            } else {
                #pragma unroll
                for (int e = 0; e < 8; ++e) {
                    int i = s0 + e - PADW;
                    int j = (i < 0) ? -i : ((i >= SEG) ? (2 * SEG - 2 - i) : i);
                    r[e] = f2bf(wav[(size_t)b * SEG + j]);
                }
            }
        }
        *(uint4*)(wp2 + (size_t)b * WPB2 + (size_t)chunk * 8) = *(const uint4*)r;
    } else if (bid < PAD_BLKS + BTF_BLKS) {
        // BTf frag-major: ((vfrag*32 + kstep)*64 + lane)*8; vfrag = mat*16+ntile
        int idx8 = (bid - PAD_BLKS) * 256 + tid;
        int lane  = idx8 & 63;
        int kstep = (idx8 >> 6) & 31;
        int ntile = (idx8 >> 11) & 15;
        int mat   = idx8 >> 15;
        int bin = ntile * 16 + (lane & 15);
        int k0  = kstep * 32 + (lane >> 4) * 8;
        const float* src = (mat ? dimg : dre) + (size_t)bin * 1024 + k0;
        const float* w   = win + k0;
        uint16_t r[8];
        #pragma unroll
        for (int j = 0; j < 8; ++j) r[j] = f2bf(src[j] * w[j]);
        *(uint4*)(BTf + (size_t)idx8 * 8) = *(const uint4*)r;
    } else {
        // fbT frag-major dense: ((mt*8 + kf)*64 + lane)*8
        int idx = (bid - PAD_BLKS - BTF_BLKS) * 256 + tid;
        if (idx >= 5120) return;
        int lane = idx & 63;
        int fI = idx >> 6;
        int kf = fI & 7, mt = fI >> 3;
        int mel = mt * 16 + (lane & 15);
        int b0  = kf * 32 + (lane >> 4) * 8;
        const float* s = mfb + (size_t)mel * 513 + b0;
        uint16_t r[8];
        #pragma unroll
        for (int j = 0; j < 8; ++j) r[j] = f2bf(s[j]);
        *(uint4*)(fbT + (size_t)idx * 8) = *(const uint4*)r;
    }
}

// ==== main: block = (batch, frame-half). 512 blocks, 8 waves, 1M x 8N.
// R19 = R17 + PER-WAVE K-PHASE STAGGER: wave w processes k-steps in order
// (t + 4w) mod 32 (accumulation order irrelevant). Breaks the convoy: without
// it all 8 waves issue their 7 ds_read_b128 bursts simultaneously (LDS queue
// ~672cy, MFMA idle) then all MFMA (LDS idle) -> ~50% util. Staggered, one
// wave's LDS burst overlaps others' MFMA clusters. Offsets are wave-uniform
// scalars (readfirstlane -> SALU). Everything else identical to R17.
__global__ __launch_bounds__(512, 1) void k_main(
    const uint16_t* __restrict__ wp2, const uint16_t* __restrict__ BTf,
    const uint16_t* __restrict__ fbT, float* __restrict__ out)
{
    __shared__ uint4 smem4[57344 / 16];      // waveform [0,39936) / pw overlay
    char* smem = (char*)smem4;

    const int tid  = threadIdx.x;
    const int lane = tid & 63;
    const int wn   = tid >> 6;               // wave = N-slice
    const int l15 = lane & 15, lg = lane >> 4;
    const int b    = blockIdx.x;
    const int h    = blockIdx.y;
    const int r0   = h ? 96 : 0;             // first frame row of this half

    // ---- fill LDS rows r0..r0+117
    const uint16_t* wsrc = wp2 + (size_t)b * WPB2 + (size_t)r0 * 168;
    #pragma unroll
    for (int i = 0; i < 4; ++i)
        gload16(wsrc + (size_t)(tid + i * 512) * 8, smem + (size_t)(tid + i * 512) * 16);
    if (tid < FILLCH - 2048)                 // 448
        gload16(wsrc + (size_t)(tid + 2048) * 8, smem + (size_t)(tid + 2048) * 16);
    asm volatile("s_waitcnt vmcnt(0)" ::: "memory");
    __syncthreads();

    const uint32_t alane = (uint32_t)(l15 * ROWB + lg * 16);
    const uint16_t* bp = BTf + (size_t)(wn * 2) * 16384 + lane * 8;
    const int phs = __builtin_amdgcn_readfirstlane(wn) << 2;   // stagger 0,4,..28

    f32x4 acc[7][4];                         // nf: 0=R.nt0 1=R.nt1 2=I.nt0 3=I.nt1
    #pragma unroll
    for (int fi = 0; fi < 7; ++fi)
        #pragma unroll
        for (int nf = 0; nf < 4; ++nf)
            acc[fi][nf] = f32x4{0.f, 0.f, 0.f, 0.f};

    bf16x8 bvA[4], bvB[4], bvC[4], av[7];

    // tp = staggered k-step index (wave-uniform scalar)
    #define LOADB(dst, tp) { \
        const uint16_t* bpt = bp + (size_t)(uint32_t)(tp) * 512; \
        dst[0] = *(const bf16x8*)(bpt); \
        dst[1] = *(const bf16x8*)(bpt + 16384); \
        dst[2] = *(const bf16x8*)(bpt + 262144); \
        dst[3] = *(const bf16x8*)(bpt + 262144 + 16384); }
    #define LOADA(tp) { \
        const uint32_t q_ = (uint32_t)(tp) / 5u; \
        const uint32_t aoff_ = q_ * ROWB + ((uint32_t)(tp) - q_ * 5u) * 64u; \
        _Pragma("unroll") \
        for (int fi = 0; fi < 7; ++fi) \
            av[fi] = *(const bf16x8*)(smem + alane + aoff_ + (uint32_t)(fi * 16 * ROWB)); }
    #define MFMA28(bv) { \
        _Pragma("unroll") \
        for (int fi = 0; fi < 7; ++fi) \
            _Pragma("unroll") \
            for (int nf = 0; nf < 4; ++nf) \
                acc[fi][nf] = __builtin_amdgcn_mfma_f32_16x16x32_bf16( \
                    av[fi], bv[nf], acc[fi][nf], 0, 0, 0); }

    LOADB(bvA, (0 + phs) & 31);
    LOADB(bvB, (1 + phs) & 31);
    #pragma unroll
    for (int t = 0; t < NSTEP; ++t) {
        LOADA((t + phs) & 31);
        if (t + 2 < NSTEP) {
            const int n2 = (t + 2) % 3;
            const int tq = (t + 2 + phs) & 31;
            if      (n2 == 0) { LOADB(bvA, tq); }
            else if (n2 == 1) { LOADB(bvB, tq); }
            else              { LOADB(bvC, tq); }
        }
        const int c = t % 3;
        if      (c == 0) { MFMA28(bvA); }
        else if (c == 1) { MFMA28(bvB); }
        else             { MFMA28(bvC); }
    }
    __syncthreads();                         // waveform dead

    // ---- power -> pw[112][256] bf16, rotation-swizzled 16B slots
    #pragma unroll
    for (int fi = 0; fi < 7; ++fi)
        #pragma unroll
        for (int nt = 0; nt < 2; ++nt)
            #pragma unroll
            for (int e = 0; e < 4; ++e) {
                const int frow = fi * 16 + lg * 4 + e;
                const int bin  = (wn * 2 + nt) * 16 + l15;
                float r = acc[fi][nt][e], im = acc[fi][nt + 2][e];
                const int slot = ((bin >> 3) + frow) & 31;
                *(uint16_t*)(smem + frow * 512 + slot * 16 + (bin & 7) * 2)
                    = f2bf(r * r + im * im);
            }
    __syncthreads();

    // ---- mel GEMM: 10 mtiles x 7 ftiles x 8 kfrags; round-robin tasks
    float* obase = out + (size_t)b * (NMELS * NFRAMES);
    for (int task = wn; task < 70; task += 8) {
        const int mt = task / 7, ft = task - mt * 7;
        f32x4 d = f32x4{0.f, 0.f, 0.f, 0.f};
        const int frame = ft * 16 + l15;
        #pragma unroll
        for (int kf = 0; kf < 8; ++kf) {
            bf16x8 a = *(const bf16x8*)(fbT + (size_t)((mt * 8 + kf) * 64 + lane) * 8);
            const int slot = (kf * 4 + lg + frame) & 31;
            bf16x8 bb = *(const bf16x8*)(smem + frame * 512 + slot * 16);
            d = __builtin_amdgcn_mfma_f32_16x16x32_bf16(a, bb, d, 0, 0, 0);
        }
        const int fg = r0 + frame;
        const bool own = h ? (fg >= 104 && fg <= 200) : (fg <= 103);
        if (own) {
            #pragma unroll
            for (int e = 0; e < 4; ++e)
                obase[(mt * 16 + lg * 4 + e) * NFRAMES + fg] = d[e];
        }
    }
}

extern "C" void kernel_launch(void* const* d_in, const int* in_sizes, int n_in,
                              void* d_out, int out_size, void* d_ws, size_t ws_size,
                              hipStream_t stream) {
    const float* wav  = (const float*)d_in[0];
    const float* win  = (const float*)d_in[1];
    const float* dre  = (const float*)d_in[2];
    const float* dimg = (const float*)d_in[3];
    const float* mfb  = (const float*)d_in[4];
    float* out = (float*)d_out;

    uint8_t* ws = (uint8_t*)d_ws;
    uint16_t* BTf = (uint16_t*)ws;                           // 1 MB frag-major DFT
    uint16_t* wp2 = (uint16_t*)(ws + (1u << 20));            // 19.8 MB padded wave
    size_t off = (1u << 20) + (size_t)NBATCH * WPB2 * 2;     // 20,832,256
    uint16_t* fbT = (uint16_t*)(ws + off);                   // 80 KB frag-major mel fb

    hipLaunchKernelGGL(k_prep, dim3(PREP_GRID), dim3(256), 0, stream,
                       wav, win, dre, dimg, mfb, wp2, BTf, fbT);
    hipLaunchKernelGGL(k_main, dim3(NBATCH, 2), dim3(512), 0, stream,
                       wp2, BTf, fbT, out);
}

// Round 20
// 80.868 us; speedup vs baseline: 1.1440x; 1.0108x over previous
//
#include <hip/hip_runtime.h>
#include <stdint.h>

#define NFFT    1024
#define HOP     160
#define NMELS   160
#define SEG     32000
#define PADW    512
#define NFRAMES 201
#define NBATCH  256
#define NSTEP   32               // K-steps of 32
#define ROWB    336              // padded row bytes (160 samples + 8 pad)
#define NROWS   230
#define WPCH    (NROWS * 21)     // 4830 u4 chunks per batch
#define WPB2    (WPCH * 8)       // 38,640 halfwords per batch
#define FILLCH  2496             // chunks per half fill (118 rows + align)

using bf16x8 = __attribute__((ext_vector_type(8))) __bf16;
using f32x4  = __attribute__((ext_vector_type(4))) float;

static __device__ __forceinline__ uint16_t f2bf(float f) {
    union { float f; uint32_t u; } v; v.f = f;
    return (uint16_t)((v.u + 0x7FFFu + ((v.u >> 16) & 1u)) >> 16);
}
static __device__ __forceinline__ void gload16(const void* g, void* l) {
    __builtin_amdgcn_global_load_lds(
        (const __attribute__((address_space(1))) uint32_t*)(uintptr_t)g,
        (__attribute__((address_space(3))) uint32_t*)(uintptr_t)l,
        16, 0, 0);
}

// ==== fused prep: pad(row-layout) | btf(frag-major) | fbT(frag-major dense) ====
#define PAD_BLKS  (NBATCH * 19)   // 4864
#define BTF_BLKS  256
#define FBT_BLKS  20              // 5120 threads: 80 frags x 64 lanes
#define PREP_GRID (PAD_BLKS + BTF_BLKS + FBT_BLKS)

__global__ void k_prep(const float* __restrict__ wav, const float* __restrict__ win,
                       const float* __restrict__ dre, const float* __restrict__ dimg,
                       const float* __restrict__ mfb,
                       uint16_t* __restrict__ wp2, uint16_t* __restrict__ BTf,
                       uint16_t* __restrict__ fbT) {
    int bid = blockIdx.x, tid = threadIdx.x;
    if (bid < PAD_BLKS) {
        int b = bid / 19, ib = bid - b * 19;
        int chunk = ib * 256 + tid;
        if (chunk >= WPCH) return;
        int row = chunk / 21, cc = chunk - row * 21;
        uint16_t r[8] = {0,0,0,0,0,0,0,0};
        if (cc < 20) {
            int s0 = row * 160 + cc * 8;
            if (s0 >= PADW && s0 + 8 <= PADW + SEG) {
                const float* s = wav + (size_t)b * SEG + (s0 - PADW);
                float4 v0 = *(const float4*)s;
                float4 v1 = *(const float4*)(s + 4);
                r[0]=f2bf(v0.x); r[1]=f2bf(v0.y); r[2]=f2bf(v0.z); r[3]=f2bf(v0.w);
                r[4]=f2bf(v1.x); r[5]=f2bf(v1.y); r[6]=f2bf(v1.z); r[7]=f2bf(v1.w);
            } else {
                #pragma unroll
                for (int e = 0; e < 8; ++e) {
                    int i = s0 + e - PADW;
                    int j = (i < 0) ? -i : ((i >= SEG) ? (2 * SEG - 2 - i) : i);
                    r[e] = f2bf(wav[(size_t)b * SEG + j]);
                }
            }
        }
        *(uint4*)(wp2 + (size_t)b * WPB2 + (size_t)chunk * 8) = *(const uint4*)r;
    } else if (bid < PAD_BLKS + BTF_BLKS) {
        // BTf frag-major: ((vfrag*32 + kstep)*64 + lane)*8; vfrag = mat*16+ntile
        int idx8 = (bid - PAD_BLKS) * 256 + tid;
        int lane  = idx8 & 63;
        int kstep = (idx8 >> 6) & 31;
        int ntile = (idx8 >> 11) & 15;
        int mat   = idx8 >> 15;
        int bin = ntile * 16 + (lane & 15);
        int k0  = kstep * 32 + (lane >> 4) * 8;
        const float* src = (mat ? dimg : dre) + (size_t)bin * 1024 + k0;
        const float* w   = win + k0;
        uint16_t r[8];
        #pragma unroll
        for (int j = 0; j < 8; ++j) r[j] = f2bf(src[j] * w[j]);
        *(uint4*)(BTf + (size_t)idx8 * 8) = *(const uint4*)r;
    } else {
        // fbT frag-major dense: ((mt*8 + kf)*64 + lane)*8
        int idx = (bid - PAD_BLKS - BTF_BLKS) * 256 + tid;
        if (idx >= 5120) return;
        int lane = idx & 63;
        int fI = idx >> 6;
        int kf = fI & 7, mt = fI >> 3;
        int mel = mt * 16 + (lane & 15);
        int b0  = kf * 32 + (lane >> 4) * 8;
        const float* s = mfb + (size_t)mel * 513 + b0;
        uint16_t r[8];
        #pragma unroll
        for (int j = 0; j < 8; ++j) r[j] = f2bf(s[j]);
        *(uint4*)(fbT + (size_t)idx * 8) = *(const uint4*)r;
    }
}

// ==== main: block = (batch, frame-half). 512 blocks, 1024 threads = 16 WAVES
// (4 waves/SIMD). R20 theory: single-wave MFMA issue cadence can't saturate
// the matrix pipe; all 2-wave/SIMD variants pinned at ~2400cy/step vs 1086
// pipe-bound. 1M x 16N: wave wn owns ALL 7 M-frags x bin-tile wn (16 bins,
// R vfrag wn + I vfrag 16+wn) -> acc 7x2x4 = 56 AGPR; ~60 arch VGPR; fits the
// 128-reg cap at 4 waves/SIMD. B single-buffered (TLP from 4 waves hides L2
// latency). Barrier-free fully-unrolled K-loop, compile-time A offsets.
// Epilogue: power (rotation-swizzled bf16 pw) + mel MFMA GEMM + masked stores.
__global__ __launch_bounds__(1024, 1) void k_main(
    const uint16_t* __restrict__ wp2, const uint16_t* __restrict__ BTf,
    const uint16_t* __restrict__ fbT, float* __restrict__ out)
{
    __shared__ uint4 smem4[57344 / 16];      // waveform [0,39936) / pw overlay
    char* smem = (char*)smem4;

    const int tid  = threadIdx.x;
    const int lane = tid & 63;
    const int wn   = tid >> 6;               // wave 0..15 = bin-tile
    const int l15 = lane & 15, lg = lane >> 4;
    const int b    = blockIdx.x;
    const int h    = blockIdx.y;
    const int r0   = h ? 96 : 0;             // first frame row of this half

    // ---- fill LDS rows r0..r0+117 (2478 chunks; 1024 threads)
    const uint16_t* wsrc = wp2 + (size_t)b * WPB2 + (size_t)r0 * 168;
    gload16(wsrc + (size_t)tid * 8,          smem + (size_t)tid * 16);
    gload16(wsrc + (size_t)(tid + 1024) * 8, smem + (size_t)(tid + 1024) * 16);
    if (tid < FILLCH - 2048)                 // 448 (wave-aligned)
        gload16(wsrc + (size_t)(tid + 2048) * 8, smem + (size_t)(tid + 2048) * 16);
    asm volatile("s_waitcnt vmcnt(0)" ::: "memory");
    __syncthreads();

    const uint32_t alane = (uint32_t)(l15 * ROWB + lg * 16);
    const uint16_t* bp = BTf + (size_t)wn * 16384 + lane * 8;  // R vfrag wn

    f32x4 acc[7][2];                         // [fi][0]=R, [fi][1]=I
    #pragma unroll
    for (int fi = 0; fi < 7; ++fi) {
        acc[fi][0] = f32x4{0.f, 0.f, 0.f, 0.f};
        acc[fi][1] = f32x4{0.f, 0.f, 0.f, 0.f};
    }

    // ---- K-loop: barrier-free, fully unrolled; B single-buffered (TLP covers)
    #pragma unroll
    for (int t = 0; t < NSTEP; ++t) {
        bf16x8 bvR = *(const bf16x8*)(bp + (size_t)t * 512);
        bf16x8 bvI = *(const bf16x8*)(bp + 262144 + (size_t)t * 512);
        const uint32_t aoff = (uint32_t)((t / 5) * ROWB + ((32 * t) % 160) * 2);
        bf16x8 av[7];
        #pragma unroll
        for (int fi = 0; fi < 7; ++fi)
            av[fi] = *(const bf16x8*)(smem + alane + aoff + (uint32_t)(fi * 16 * ROWB));
        #pragma unroll
        for (int fi = 0; fi < 7; ++fi) {
            acc[fi][0] = __builtin_amdgcn_mfma_f32_16x16x32_bf16(av[fi], bvR, acc[fi][0], 0, 0, 0);
            acc[fi][1] = __builtin_amdgcn_mfma_f32_16x16x32_bf16(av[fi], bvI, acc[fi][1], 0, 0, 0);
        }
    }
    __syncthreads();                         // waveform dead

    // ---- power -> pw[112][256] bf16, rotation-swizzled 16B slots
    #pragma unroll
    for (int fi = 0; fi < 7; ++fi)
        #pragma unroll
        for (int e = 0; e < 4; ++e) {
            const int frow = fi * 16 + lg * 4 + e;
            const int bin  = wn * 16 + l15;
            float r = acc[fi][0][e], im = acc[fi][1][e];
            const int slot = ((bin >> 3) + frow) & 31;
            *(uint16_t*)(smem + frow * 512 + slot * 16 + (bin & 7) * 2)
                = f2bf(r * r + im * im);
        }
    __syncthreads();

    // ---- mel GEMM: 10 mtiles x 7 ftiles x 8 kfrags; round-robin over 16 waves
    float* obase = out + (size_t)b * (NMELS * NFRAMES);
    for (int task = wn; task < 70; task += 16) {
        const int mt = task / 7, ft = task - mt * 7;
        f32x4 d = f32x4{0.f, 0.f, 0.f, 0.f};
        const int frame = ft * 16 + l15;
        #pragma unroll
        for (int kf = 0; kf < 8; ++kf) {
            bf16x8 a = *(const bf16x8*)(fbT + (size_t)((mt * 8 + kf) * 64 + lane) * 8);
            const int slot = (kf * 4 + lg + frame) & 31;
            bf16x8 bb = *(const bf16x8*)(smem + frame * 512 + slot * 16);
            d = __builtin_amdgcn_mfma_f32_16x16x32_bf16(a, bb, d, 0, 0, 0);
        }
        const int fg = r0 + frame;
        const bool own = h ? (fg >= 104 && fg <= 200) : (fg <= 103);
        if (own) {
            #pragma unroll
            for (int e = 0; e < 4; ++e)
                obase[(mt * 16 + lg * 4 + e) * NFRAMES + fg] = d[e];
        }
    }
}

extern "C" void kernel_launch(void* const* d_in, const int* in_sizes, int n_in,
                              void* d_out, int out_size, void* d_ws, size_t ws_size,
                              hipStream_t stream) {
    const float* wav  = (const float*)d_in[0];
    const float* win  = (const float*)d_in[1];
    const float* dre  = (const float*)d_in[2];
    const float* dimg = (const float*)d_in[3];
    const float* mfb  = (const float*)d_in[4];
    float* out = (float*)d_out;

    uint8_t* ws = (uint8_t*)d_ws;
    uint16_t* BTf = (uint16_t*)ws;                           // 1 MB frag-major DFT
    uint16_t* wp2 = (uint16_t*)(ws + (1u << 20));            // 19.8 MB padded wave
    size_t off = (1u << 20) + (size_t)NBATCH * WPB2 * 2;     // 20,832,256
    uint16_t* fbT = (uint16_t*)(ws + off);                   // 80 KB frag-major mel fb

    hipLaunchKernelGGL(k_prep, dim3(PREP_GRID), dim3(256), 0, stream,
                       wav, win, dre, dimg, mfb, wp2, BTf, fbT);
    hipLaunchKernelGGL(k_main, dim3(NBATCH, 2), dim3(1024), 0, stream,
                       wp2, BTf, fbT, out);
}

// Round 21
// 75.510 us; speedup vs baseline: 1.2251x; 1.0710x over previous
//
#include <hip/hip_runtime.h>
#include <stdint.h>

#define NFFT    1024
#define HOP     160
#define NMELS   160
#define SEG     32000
#define PADW    512
#define NFRAMES 201
#define NBATCH  256
#define NSTEP   32               // K-steps of 32
#define ROWB    336              // padded row bytes (160 samples + 8 pad)
#define NROWS   230
#define WPCH    (NROWS * 21)     // 4830 u4 chunks per batch
#define WPB2    (WPCH * 8)       // 38,640 halfwords per batch
#define FILLCH  2496             // chunks per half fill (118 rows + align)

using bf16x8 = __attribute__((ext_vector_type(8))) __bf16;
using f32x4  = __attribute__((ext_vector_type(4))) float;

static __device__ __forceinline__ uint16_t f2bf(float f) {
    union { float f; uint32_t u; } v; v.f = f;
    return (uint16_t)((v.u + 0x7FFFu + ((v.u >> 16) & 1u)) >> 16);
}
static __device__ __forceinline__ void gload16(const void* g, void* l) {
    __builtin_amdgcn_global_load_lds(
        (const __attribute__((address_space(1))) uint32_t*)(uintptr_t)g,
        (__attribute__((address_space(3))) uint32_t*)(uintptr_t)l,
        16, 0, 0);
}

// ==== fused prep: pad | btf | fbT_A | fbT_B | zero-mel111 ====
// Mel band split (verified: only mel 111 straddles bin 128; mel 110 max bin
// 127, mel 112 min bin 128): group A = bins 0..127, mels 0..111 (111 partial);
// group B = bins 128..255, mels 96..159 with rows <111 zeroed (111 partial).
#define PAD_BLKS  (NBATCH * 19)   // 4864
#define BTF_BLKS  256
#define FBTA_BLKS 7               // 1792 threads: 7 mt x 4 kf x 64 lanes
#define FBTB_BLKS 4               // 1024 threads: 4 mt x 4 kf x 64 lanes
#define ZR_BLKS   256             // zero out[:,111,:]
#define PREP_GRID (PAD_BLKS + BTF_BLKS + FBTA_BLKS + FBTB_BLKS + ZR_BLKS)

__global__ void k_prep(const float* __restrict__ wav, const float* __restrict__ win,
                       const float* __restrict__ dre, const float* __restrict__ dimg,
                       const float* __restrict__ mfb,
                       uint16_t* __restrict__ wp2, uint16_t* __restrict__ BTf,
                       uint16_t* __restrict__ fbTA, uint16_t* __restrict__ fbTB,
                       float* __restrict__ out) {
    int bid = blockIdx.x, tid = threadIdx.x;
    if (bid < PAD_BLKS) {
        int b = bid / 19, ib = bid - b * 19;
        int chunk = ib * 256 + tid;
        if (chunk >= WPCH) return;
        int row = chunk / 21, cc = chunk - row * 21;
        uint16_t r[8] = {0,0,0,0,0,0,0,0};
        if (cc < 20) {
            int s0 = row * 160 + cc * 8;
            if (s0 >= PADW && s0 + 8 <= PADW + SEG) {
                const float* s = wav + (size_t)b * SEG + (s0 - PADW);
                float4 v0 = *(const float4*)s;
                float4 v1 = *(const float4*)(s + 4);
                r[0]=f2bf(v0.x); r[1]=f2bf(v0.y); r[2]=f2bf(v0.z); r[3]=f2bf(v0.w);
                r[4]=f2bf(v1.x); r[5]=f2bf(v1.y); r[6]=f2bf(v1.z); r[7]=f2bf(v1.w);
            } else {
                #pragma unroll
                for (int e = 0; e < 8; ++e) {
                    int i = s0 + e - PADW;
                    int j = (i < 0) ? -i : ((i >= SEG) ? (2 * SEG - 2 - i) : i);
                    r[e] = f2bf(wav[(size_t)b * SEG + j]);
                }
            }
        }
        *(uint4*)(wp2 + (size_t)b * WPB2 + (size_t)chunk * 8) = *(const uint4*)r;
    } else if (bid < PAD_BLKS + BTF_BLKS) {
        // BTf frag-major: ((vfrag*32 + kstep)*64 + lane)*8; vfrag = mat*16+ntile
        int idx8 = (bid - PAD_BLKS) * 256 + tid;
        int lane  = idx8 & 63;
        int kstep = (idx8 >> 6) & 31;
        int ntile = (idx8 >> 11) & 15;
        int mat   = idx8 >> 15;
        int bin = ntile * 16 + (lane & 15);
        int k0  = kstep * 32 + (lane >> 4) * 8;
        const float* src = (mat ? dimg : dre) + (size_t)bin * 1024 + k0;
        const float* w   = win + k0;
        uint16_t r[8];
        #pragma unroll
        for (int j = 0; j < 8; ++j) r[j] = f2bf(src[j] * w[j]);
        *(uint4*)(BTf + (size_t)idx8 * 8) = *(const uint4*)r;
    } else if (bid < PAD_BLKS + BTF_BLKS + FBTA_BLKS) {
        // fbT_A: ((mt*4 + kf)*64 + lane)*8; mel = mt*16+l15 (0..111), bin<128
        int idx = (bid - PAD_BLKS - BTF_BLKS) * 256 + tid;
        if (idx >= FBTA_BLKS * 256) return;
        int lane = idx & 63;
        int fI = idx >> 6;                    // 0..27
        int kf = fI & 3, mt = fI >> 2;        // mt 0..6
        int mel = mt * 16 + (lane & 15);
        int bin = kf * 32 + (lane >> 4) * 8;
        const float* s = mfb + (size_t)mel * 513 + bin;
        uint16_t r[8];
        #pragma unroll
        for (int j = 0; j < 8; ++j) r[j] = f2bf(s[j]);
        *(uint4*)(fbTA + (size_t)idx * 8) = *(const uint4*)r;
    } else if (bid < PAD_BLKS + BTF_BLKS + FBTA_BLKS + FBTB_BLKS) {
        // fbT_B: mel = 96+mt*16+l15 (rows <111 zeroed), bin = 128 + kf*32+lg*8
        int idx = (bid - PAD_BLKS - BTF_BLKS - FBTA_BLKS) * 256 + tid;
        if (idx >= FBTB_BLKS * 256) return;
        int lane = idx & 63;
        int fI = idx >> 6;                    // 0..15
        int kf = fI & 3, mt = fI >> 2;        // mt 0..3
        int mel = 96 + mt * 16 + (lane & 15);
        int bin = 128 + kf * 32 + (lane >> 4) * 8;
        const float* s = mfb + (size_t)mel * 513 + bin;
        uint16_t r[8];
        #pragma unroll
        for (int j = 0; j < 8; ++j) r[j] = (mel >= 111) ? f2bf(s[j]) : (uint16_t)0;
        *(uint4*)(fbTB + (size_t)idx * 8) = *(const uint4*)r;
    } else {
        // zero the mel-111 row (atomicAdd target from both groups)
        int b = bid - (PAD_BLKS + BTF_BLKS + FBTA_BLKS + FBTB_BLKS);
        if (tid < NFRAMES)
            out[(size_t)b * (NMELS * NFRAMES) + 111 * NFRAMES + tid] = 0.f;
    }
}

// ==== main: block = (batch, frame-half, mel-group). 1024 blocks, 512 threads,
// 8 waves, TWO blocks co-resident per CU (acc 56 AGPR + ~60 arch < 128 cap at
// __launch_bounds__(512,4)). Co-residency overlaps one block's fill/epilogue
// with the other's K-loop — the phase-serialization 1-block/CU variants paid.
// Wave wn owns ALL 7 M-frags x bin-tile (grp*8 + wn): R vfrag + I vfrag.
// K-loop: barrier-free, fully unrolled, B single-buffered (4 waves/SIMD TLP).
// Epilogue: power -> pw[112][128] bf16 (rotation swizzle, 16 slots/row), mel
// MFMA GEMM vs group fbT (K=128), disjoint mel-row stores; mel 111 atomicAdd.
__global__ __launch_bounds__(512, 4) void k_main(
    const uint16_t* __restrict__ wp2, const uint16_t* __restrict__ BTf,
    const uint16_t* __restrict__ fbTA, const uint16_t* __restrict__ fbTB,
    float* __restrict__ out)
{
    __shared__ uint4 smem4[FILLCH];          // 39,936 B: waveform / pw overlay
    char* smem = (char*)smem4;

    const int tid  = threadIdx.x;
    const int lane = tid & 63;
    const int wn   = tid >> 6;               // wave 0..7 = bin-tile within group
    const int l15 = lane & 15, lg = lane >> 4;
    const int b    = blockIdx.x;
    const int h    = blockIdx.y;             // frame-half
    const int grp  = blockIdx.z;             // mel/bin group
    const int r0   = h ? 96 : 0;

    // ---- fill LDS rows r0..r0+117 (2478 chunks + aligned tail)
    const uint16_t* wsrc = wp2 + (size_t)b * WPB2 + (size_t)r0 * 168;
    #pragma unroll
    for (int i = 0; i < 4; ++i)
        gload16(wsrc + (size_t)(tid + i * 512) * 8, smem + (size_t)(tid + i * 512) * 16);
    if (tid < FILLCH - 2048)                 // 448
        gload16(wsrc + (size_t)(tid + 2048) * 8, smem + (size_t)(tid + 2048) * 16);
    asm volatile("s_waitcnt vmcnt(0)" ::: "memory");
    __syncthreads();

    const uint32_t alane = (uint32_t)(l15 * ROWB + lg * 16);
    const uint16_t* bp = BTf + (size_t)(grp * 8 + wn) * 16384 + lane * 8;

    f32x4 acc[7][2];                         // [fi][0]=R, [fi][1]=I
    #pragma unroll
    for (int fi = 0; fi < 7; ++fi) {
        acc[fi][0] = f32x4{0.f, 0.f, 0.f, 0.f};
        acc[fi][1] = f32x4{0.f, 0.f, 0.f, 0.f};
    }

    // ---- K-loop: barrier-free, fully unrolled
    #pragma unroll
    for (int t = 0; t < NSTEP; ++t) {
        bf16x8 bvR = *(const bf16x8*)(bp + (size_t)t * 512);
        bf16x8 bvI = *(const bf16x8*)(bp + 262144 + (size_t)t * 512);
        const uint32_t aoff = (uint32_t)((t / 5) * ROWB + ((32 * t) % 160) * 2);
        bf16x8 av[7];
        #pragma unroll
        for (int fi = 0; fi < 7; ++fi)
            av[fi] = *(const bf16x8*)(smem + alane + aoff + (uint32_t)(fi * 16 * ROWB));
        #pragma unroll
        for (int fi = 0; fi < 7; ++fi) {
            acc[fi][0] = __builtin_amdgcn_mfma_f32_16x16x32_bf16(av[fi], bvR, acc[fi][0], 0, 0, 0);
            acc[fi][1] = __builtin_amdgcn_mfma_f32_16x16x32_bf16(av[fi], bvI, acc[fi][1], 0, 0, 0);
        }
    }
    __syncthreads();                         // waveform dead

    // ---- power -> pw[112][128] bf16, rotation swizzle (16 slots of 16B/row)
    #pragma unroll
    for (int fi = 0; fi < 7; ++fi)
        #pragma unroll
        for (int e = 0; e < 4; ++e) {
            const int frow = fi * 16 + lg * 4 + e;
            const int binl = wn * 16 + l15;   // local bin 0..127
            float r = acc[fi][0][e], im = acc[fi][1][e];
            const int slot = ((binl >> 3) + frow) & 15;
            *(uint16_t*)(smem + frow * 256 + slot * 16 + (binl & 7) * 2)
                = f2bf(r * r + im * im);
        }
    __syncthreads();

    // ---- mel GEMM (K=128): A: 7 mt x 7 ft; B: 4 mt x 7 ft
    const uint16_t* fbt = grp ? fbTB : fbTA;
    const int ntask = grp ? 28 : 49;
    const int mbase = grp ? 96 : 0;
    float* obase = out + (size_t)b * (NMELS * NFRAMES);
    for (int task = wn; task < ntask; task += 8) {
        const int mt = task / 7, ft = task - mt * 7;
        f32x4 d = f32x4{0.f, 0.f, 0.f, 0.f};
        const int frame = ft * 16 + l15;
        #pragma unroll
        for (int kf = 0; kf < 4; ++kf) {
            bf16x8 a = *(const bf16x8*)(fbt + (size_t)((mt * 4 + kf) * 64 + lane) * 8);
            const int slot = (kf * 4 + lg + frame) & 15;
            bf16x8 bb = *(const bf16x8*)(smem + frame * 256 + slot * 16);
            d = __builtin_amdgcn_mfma_f32_16x16x32_bf16(a, bb, d, 0, 0, 0);
        }
        const int fg = r0 + frame;
        const bool own = h ? (fg >= 104 && fg <= 200) : (fg <= 103);
        if (own) {
            #pragma unroll
            for (int e = 0; e < 4; ++e) {
                const int mel = mbase + mt * 16 + lg * 4 + e;
                float* dst = obase + (size_t)mel * NFRAMES + fg;
                if (mel == 111)      atomicAdd(dst, d[e]);
                else if (grp == 0 ? (mel <= 110) : (mel >= 112)) *dst = d[e];
            }
        }
    }
}

extern "C" void kernel_launch(void* const* d_in, const int* in_sizes, int n_in,
                              void* d_out, int out_size, void* d_ws, size_t ws_size,
                              hipStream_t stream) {
    const float* wav  = (const float*)d_in[0];
    const float* win  = (const float*)d_in[1];
    const float* dre  = (const float*)d_in[2];
    const float* dimg = (const float*)d_in[3];
    const float* mfb  = (const float*)d_in[4];
    float* out = (float*)d_out;

    uint8_t* ws = (uint8_t*)d_ws;
    uint16_t* BTf = (uint16_t*)ws;                           // 1 MB frag-major DFT
    uint16_t* wp2 = (uint16_t*)(ws + (1u << 20));            // 19.8 MB padded wave
    size_t off = (1u << 20) + (size_t)NBATCH * WPB2 * 2;     // 20,832,256
    uint16_t* fbTA = (uint16_t*)(ws + off);                  // 28,672 B
    uint16_t* fbTB = (uint16_t*)(ws + off + 28672);          // 16,384 B

    hipLaunchKernelGGL(k_prep, dim3(PREP_GRID), dim3(256), 0, stream,
                       wav, win, dre, dimg, mfb, wp2, BTf, fbTA, fbTB, out);
    hipLaunchKernelGGL(k_main, dim3(NBATCH, 2, 2), dim3(512), 0, stream,
                       wp2, BTf, fbTA, fbTB, out);
}